// Round 10
// baseline (297.331 us; speedup 1.0000x reference)
//
#include <hip/hip_runtime.h>

// Problem constants
#define BATCH   4
#define SEQ     2048
#define DMODEL  1024
#define NHEADS  16
#define HDIM    64
// SCALE * log2(e) folded into Q at the GEMM epilogue: exp(s*0.125) = exp2(s*QSC)
#define QSC     0.18033688f

typedef short s16x8 __attribute__((ext_vector_type(8)));
typedef float f32x4 __attribute__((ext_vector_type(4)));
typedef const __attribute__((address_space(1))) unsigned int* gas_t;
typedef __attribute__((address_space(3))) unsigned int* las_t;

__device__ inline unsigned short f2bf(float f) {
    unsigned int u = __float_as_uint(f);
    u += 0x7FFF + ((u >> 16) & 1);   // RNE
    return (unsigned short)(u >> 16);
}

__device__ __forceinline__ float exp2_fast(float x) {
#if __has_builtin(__builtin_amdgcn_exp2f)
    return __builtin_amdgcn_exp2f(x);
#else
    return exp2f(x);
#endif
}

__device__ __forceinline__ float rcp_fast(float x) {
#if __has_builtin(__builtin_amdgcn_rcpf)
    return __builtin_amdgcn_rcpf(x);
#else
    return 1.0f / x;
#endif
}

// pack two positive floats to bf16x2 (round-half-up), lo in low 16 bits
__device__ __forceinline__ unsigned int pack_bf16x2(float lo, float hi) {
    unsigned int a = __float_as_uint(lo) + 0x8000u;
    unsigned int b = __float_as_uint(hi) + 0x8000u;
#if __has_builtin(__builtin_amdgcn_perm)
    return __builtin_amdgcn_perm(b, a, 0x07060302u);
#else
    return (a >> 16) | (b & 0xFFFF0000u);
#endif
}

// ---------------- fp32 -> bf16 convert (4 elems/thread), both tensors ------
// R8-proven: merged into one dispatch (saves a launch, ~6 us).
__global__ void cvt_bf16_2(const float* __restrict__ a,
                           unsigned short* __restrict__ oa, int n4a,
                           const float* __restrict__ bsrc,
                           unsigned short* __restrict__ ob, int n4b) {
    int i = blockIdx.x * blockDim.x + threadIdx.x;
    if (i < n4a) {
        float4 v = ((const float4*)a)[i];
        ushort4 o;
        o.x = f2bf(v.x); o.y = f2bf(v.y); o.z = f2bf(v.z); o.w = f2bf(v.w);
        ((ushort4*)oa)[i] = o;
    } else {
        int j = i - n4a;
        if (j < n4b) {
            float4 v = ((const float4*)bsrc)[j];
            ushort4 o;
            o.x = f2bf(v.x); o.y = f2bf(v.y); o.z = f2bf(v.z); o.w = f2bf(v.w);
            ((ushort4*)ob)[j] = o;
        }
    }
}

// ---------------- QKV projection GEMM ----------------
// R2-proven: staging via global_load_lds (async DMA) + XCD swizzle.
// R6/R7-kept: double-buffer + chunk-XOR bank swizzle. Untouched this round.
__global__ __launch_bounds__(256) void qkv_gemm(
    const unsigned short* __restrict__ Xb,
    const unsigned short* __restrict__ Wb,
    unsigned short* __restrict__ Qo,
    unsigned short* __restrict__ Ko,
    unsigned short* __restrict__ Vt)
{
    __shared__ __align__(16) unsigned short As[2 * 128 * 32];
    __shared__ __align__(16) unsigned short Bs[2 * 128 * 32];

    const int t    = threadIdx.x;
    // XCD swizzle: flat in dispatch order (x fastest), 8 XCDs round-robin
    const int flat = blockIdx.y * 24 + blockIdx.x;
    const int sw   = (flat & 7) * 192 + (flat >> 3);
    const int m0   = (sw / 24) * 128;
    const int n0   = (sw % 24) * 128;

    const int wid  = t >> 6;
    const int lane = t & 63;
    const int l15  = lane & 15;
    const int quad = lane >> 4;
    const int wm   = (wid >> 1) * 64;
    const int wn   = (wid & 1) * 64;

    // staging: wave w covers tile rows w*32 .. w*32+31 (2 chunks of 16 rows)
    const int rA   = wid * 32 + (lane >> 2);      // + rd*16 (rd*16 doesn't change (rA>>1)&3)
    // inverse-swizzled global source column: chunk (lane&3) ^ ((rA>>1)&3)
    const int kcol_phys = (lane & 3) * 8;                          // LDS (lane-linear)
    const int kcol_src  = ((lane & 3) ^ ((rA >> 1) & 3)) * 8;      // global
    const unsigned short* gA = &Xb[(size_t)(m0 + rA) * 1024 + kcol_src];
    const unsigned short* gB = &Wb[(size_t)(n0 + rA) * 1024 + kcol_src];

    // swizzled read chunk: logical chunk = quad, phys = quad ^ ((l15>>1)&3)
    const int cswq = (quad ^ ((l15 >> 1) & 3)) * 8;

    f32x4 acc[4][4] = {};

    auto stage = [&](int k0, int bufE) {
        #pragma unroll
        for (int rd = 0; rd < 2; rd++) {
            __builtin_amdgcn_global_load_lds(
                (gas_t)(const void*)(gA + rd * 16 * 1024 + k0),
                (las_t)(void*)&As[bufE + (rA + rd * 16) * 32 + kcol_phys], 16, 0, 0);
            __builtin_amdgcn_global_load_lds(
                (gas_t)(const void*)(gB + rd * 16 * 1024 + k0),
                (las_t)(void*)&Bs[bufE + (rA + rd * 16) * 32 + kcol_phys], 16, 0, 0);
        }
    };

    auto comp = [&](int bufE) {
        s16x8 af[4], bf[4];
        #pragma unroll
        for (int mt = 0; mt < 4; mt++)
            af[mt] = *(const s16x8*)&As[bufE + (wm + mt * 16 + l15) * 32 + cswq];
        #pragma unroll
        for (int nt = 0; nt < 4; nt++)
            bf[nt] = *(const s16x8*)&Bs[bufE + (wn + nt * 16 + l15) * 32 + cswq];
        #pragma unroll
        for (int mt = 0; mt < 4; mt++)
            #pragma unroll
            for (int nt = 0; nt < 4; nt++)
                acc[mt][nt] = __builtin_amdgcn_mfma_f32_16x16x32_bf16(
                    af[mt], bf[nt], acc[mt][nt], 0, 0, 0);
    };

    // prologue
    stage(0, 0);
    __syncthreads();            // vmcnt(0) drain + barrier: buf0 ready

    #pragma unroll 1
    for (int k0 = 0; k0 < 1024; k0 += 64) {
        stage(k0 + 32, 4096);   // k0+32 <= 992 always
        comp(0);
        __syncthreads();        // drains buf1 DMA; buf0 compute done
        if (k0 + 64 < 1024) stage(k0 + 64, 0);
        comp(4096);
        __syncthreads();
    }

    #pragma unroll
    for (int mt = 0; mt < 4; mt++) {
        const int mbase = m0 + wm + mt * 16 + quad * 4;
        const int b     = mbase >> 11;
        const int nbase = mbase & 2047;
        #pragma unroll
        for (int nt = 0; nt < 4; nt++) {
            const int o  = n0 + wn + nt * 16 + l15;
            const int p  = o >> 10;
            const int oo = o & 1023;
            const int h  = oo >> 6;
            const int d  = oo & 63;
            if (p == 0) {
                #pragma unroll
                for (int r = 0; r < 4; r++)
                    Qo[((size_t)(b * 16 + h) * 2048 + nbase + r) * 64 + d] =
                        f2bf(acc[mt][nt][r] * QSC);
            } else if (p == 1) {
                #pragma unroll
                for (int r = 0; r < 4; r++)
                    Ko[((size_t)(b * 16 + h) * 2048 + nbase + r) * 64 + d] =
                        f2bf(acc[mt][nt][r]);
            } else {
                ushort4 v4;
                v4.x = f2bf(acc[mt][nt][0]);
                v4.y = f2bf(acc[mt][nt][1]);
                v4.z = f2bf(acc[mt][nt][2]);
                v4.w = f2bf(acc[mt][nt][3]);
                *(ushort4*)&Vt[((size_t)(b * 16 + h) * 64 + d) * 2048 + nbase] = v4;
            }
        }
    }
}

// ---------------- fused attention ----------------
// R10 (= R9 resubmit): V no longer LDS-staged (Common-mistake #7: V head =
// 256KB, L2-fits, 16 q-blocks/head reuse). vb fragments read direct from
// global V^T — identical values (desk-checked vs unswizzled csw mapping).
// Halves the staging DMA + barrier-drain weight; LDS 50KB -> 34KB ->
// 4 blocks/CU (16 waves/CU, +33% occupancy for the serial softmax chain).
// setprio reverted (R8: slightly negative; 4-wave barrier-lockstep is
// m190's null regime).
// LDS map (ushort elems): K0@0, K1@4096, P@8192+w*2304.
#define PSTRIDE 72
#define PBASE   8192

__global__ __launch_bounds__(256) void attn(
    const unsigned short* __restrict__ Q,
    const unsigned short* __restrict__ K,
    const unsigned short* __restrict__ Vt,
    float* __restrict__ out)
{
    __shared__ __align__(16) unsigned short LDS[PBASE + 4 * 32 * PSTRIDE];

    const int t    = threadIdx.x;
    const int w    = t >> 6;
    const int lane = t & 63;
    const int l15  = lane & 15;
    const int quad = lane >> 4;
    const int head = blockIdx.y;            // b*16 + h
    const int b    = head >> 4;
    const int h    = head & 15;
    const int q0   = blockIdx.x * 128 + w * 32;

    const unsigned short* Qh = Q  + (size_t)head * 2048 * 64;
    const unsigned short* Kh = K  + (size_t)head * 2048 * 64;
    const unsigned short* Vh = Vt + (size_t)head * 64 * 2048;

    // ---- K staging source addresses (per thread, lane-linear LDS dst) ----
    // phys chunk i = rd*256 + t holds logical (row=i>>3, col=(i&7)^(row&7))
    const int r0 = t >> 3;                    // 0..31 (rd=1 adds 32)
    const int c0 = (t & 7) ^ (r0 & 7);
    const unsigned short* srcK = Kh + r0 * 64 + c0 * 8;

    auto stageK = [&](int kt, int bufE) {
        #pragma unroll
        for (int rd = 0; rd < 2; rd++) {
            __builtin_amdgcn_global_load_lds(
                (gas_t)(const void*)(srcK + kt * 4096 + rd * 2048),
                (las_t)(void*)&LDS[bufE + rd * 2048 + w * 512], 16, 0, 0);
        }
    };

    // Q fragments (pre-scaled by QSC in gemm), B-operand role
    s16x8 qb[2][2];
    #pragma unroll
    for (int mt = 0; mt < 2; mt++)
        #pragma unroll
        for (int kc = 0; kc < 2; kc++)
            qb[mt][kc] = *(const s16x8*)&Qh[(size_t)(q0 + mt * 16 + l15) * 64 + kc * 32 + quad * 8];

    // ones B-fragment (bf16 1.0) for MFMA row-sums
    s16x8 onesf;
    #pragma unroll
    for (int i = 0; i < 8; i++) onesf[i] = (short)0x3F80;
    const f32x4 fz = {0.f, 0.f, 0.f, 0.f};

    f32x4 y[2][4] = {};
    f32x4 ysum[2] = {};
    unsigned short* P = &LDS[PBASE + w * (32 * PSTRIDE)];

    // swizzled in-tile column offsets (elems) for kc=0/1 (K LDS reads only)
    const int x7   = l15 & 7;
    const int csw0 = (quad ^ x7) * 8;
    const int csw1 = ((4 + quad) ^ x7) * 8;

    // V direct-read base: V^T row d = dt*16+l15, col n = kt*64 + kc*32 + quad*8
    const unsigned short* vbase = Vh + (size_t)l15 * 2048 + quad * 8;

    auto compute = [&](int kt, int bufE) {
        // V fragments direct from global (L2-resident; issue first to
        // overlap load latency with QK^T + softmax)
        s16x8 vb[4][2];
        #pragma unroll
        for (int dt = 0; dt < 4; dt++)
            #pragma unroll
            for (int kc = 0; kc < 2; kc++)
                vb[dt][kc] = *(const s16x8*)&vbase[(size_t)dt * 16 * 2048 + kt * 64 + kc * 32];
        // K fragments from LDS
        s16x8 kb[4][2];
        #pragma unroll
        for (int nt = 0; nt < 4; nt++) {
            const int rowb = bufE + (nt * 16 + l15) * 64;
            kb[nt][0] = *(const s16x8*)&LDS[rowb + csw0];
            kb[nt][1] = *(const s16x8*)&LDS[rowb + csw1];
        }
        // S^T = K * Q^T  (kc=0 consumes shared zero C; kc=1 accumulates)
        f32x4 st[4][2];
        #pragma unroll
        for (int nt = 0; nt < 4; nt++)
            #pragma unroll
            for (int mt = 0; mt < 2; mt++)
                st[nt][mt] = __builtin_amdgcn_mfma_f32_16x16x32_bf16(
                    kb[nt][0], qb[mt][0], fz, 0, 0, 0);
        #pragma unroll
        for (int nt = 0; nt < 4; nt++)
            #pragma unroll
            for (int mt = 0; mt < 2; mt++)
                st[nt][mt] = __builtin_amdgcn_mfma_f32_16x16x32_bf16(
                    kb[nt][1], qb[mt][1], st[nt][mt], 0, 0, 0);
        // exp2 + pack + ds_write_b64 into per-wave P region
        #pragma unroll
        for (int mt = 0; mt < 2; mt++)
            #pragma unroll
            for (int nt = 0; nt < 4; nt++) {
                float p0 = exp2_fast(st[nt][mt][0]);
                float p1 = exp2_fast(st[nt][mt][1]);
                float p2 = exp2_fast(st[nt][mt][2]);
                float p3 = exp2_fast(st[nt][mt][3]);
                uint2 u;
                u.x = pack_bf16x2(p0, p1);
                u.y = pack_bf16x2(p2, p3);
                *(uint2*)&P[(mt * 16 + l15) * PSTRIDE + nt * 16 + quad * 4] = u;
            }
        // Y += P V ; row sums via ones-MFMA (denominator = bf16 P, consistent
        // with the PV numerator)
        #pragma unroll
        for (int kc = 0; kc < 2; kc++) {
            s16x8 pa[2];
            #pragma unroll
            for (int mt = 0; mt < 2; mt++)
                pa[mt] = *(const s16x8*)&P[(mt * 16 + l15) * PSTRIDE + kc * 32 + quad * 8];
            #pragma unroll
            for (int mt = 0; mt < 2; mt++)
                ysum[mt] = __builtin_amdgcn_mfma_f32_16x16x32_bf16(
                    pa[mt], onesf, ysum[mt], 0, 0, 0);
            #pragma unroll
            for (int mt = 0; mt < 2; mt++)
                #pragma unroll
                for (int dt = 0; dt < 4; dt++)
                    y[mt][dt] = __builtin_amdgcn_mfma_f32_16x16x32_bf16(
                        pa[mt], vb[dt][kc], y[mt][dt], 0, 0, 0);
        }
    };

    // -------- prologue --------
    stageK(0, 0);
    __syncthreads();            // drain (vmcnt 0) + barrier: buf0 ready

    // -------- main loop: issue next (other buffer) -> compute -> barrier ----
    #pragma unroll 1
    for (int kt = 0; kt < 32; kt += 2) {
        stageK(kt + 1, 4096);           // kt+1 <= 31 always
        compute(kt, 0);
        __syncthreads();
        if (kt + 2 < 32) stageK(kt + 2, 0);
        compute(kt + 1, 4096);
        __syncthreads();
    }

    // ysum[mt][r] holds the full row sum for q-row = mt*16 + quad*4 + r
    float rinv[2][4];
    #pragma unroll
    for (int mt = 0; mt < 2; mt++)
        #pragma unroll
        for (int r = 0; r < 4; r++)
            rinv[mt][r] = rcp_fast(ysum[mt][r]);

    // out[b, n, h*64+d] fp32; C-layout: col=l15 -> d, row=quad*4+r -> m
    #pragma unroll
    for (int mt = 0; mt < 2; mt++)
        #pragma unroll
        for (int dt = 0; dt < 4; dt++)
            #pragma unroll
            for (int r = 0; r < 4; r++) {
                const int n = q0 + mt * 16 + quad * 4 + r;
                const int d = dt * 16 + l15;
                out[((size_t)(b * 2048 + n)) * 1024 + h * 64 + d] =
                    y[mt][dt][r] * rinv[mt][r];
            }
}

// ---------------- launch ----------------
extern "C" void kernel_launch(void* const* d_in, const int* in_sizes, int n_in,
                              void* d_out, int out_size, void* d_ws, size_t ws_size,
                              hipStream_t stream) {
    const float* X = (const float*)d_in[0];   // [4,2048,1024]
    const float* W = (const float*)d_in[1];   // [3072,1024]
    float* out = (float*)d_out;

    char* ws = (char*)d_ws;
    unsigned short* Xb = (unsigned short*)(ws);                 // 16.8 MB
    unsigned short* Wb = (unsigned short*)(ws + 16777216);      //  6.3 MB
    unsigned short* Qb = (unsigned short*)(ws + 23068672);      // 16.8 MB
    unsigned short* Kb = (unsigned short*)(ws + 39845888);      // 16.8 MB
    unsigned short* Vt = (unsigned short*)(ws + 56623104);      // 16.8 MB (ends 73.4 MB)

    cvt_bf16_2<<<dim3(11264), dim3(256), 0, stream>>>(X, Xb, 2097152, W, Wb, 786432);
    qkv_gemm<<<dim3(24, 64), dim3(256), 0, stream>>>(Xb, Wb, Qb, Kb, Vt);
    attn<<<dim3(16, 64), dim3(256), 0, stream>>>(Qb, Kb, Vt, out);
}

// Round 11
// 251.009 us; speedup vs baseline: 1.1845x; 1.1845x over previous
//
#include <hip/hip_runtime.h>

// Problem constants
#define BATCH   4
#define SEQ     2048
#define DMODEL  1024
#define NHEADS  16
#define HDIM    64
// SCALE * log2(e) folded into Q at the GEMM epilogue: exp(s*0.125) = exp2(s*QSC)
#define QSC     0.18033688f

typedef short s16x8 __attribute__((ext_vector_type(8)));
typedef float f32x4 __attribute__((ext_vector_type(4)));
typedef const __attribute__((address_space(1))) unsigned int* gas_t;
typedef __attribute__((address_space(3))) unsigned int* las_t;

__device__ inline unsigned short f2bf(float f) {
    unsigned int u = __float_as_uint(f);
    u += 0x7FFF + ((u >> 16) & 1);   // RNE
    return (unsigned short)(u >> 16);
}

__device__ __forceinline__ float exp2_fast(float x) {
#if __has_builtin(__builtin_amdgcn_exp2f)
    return __builtin_amdgcn_exp2f(x);
#else
    return exp2f(x);
#endif
}

__device__ __forceinline__ float rcp_fast(float x) {
#if __has_builtin(__builtin_amdgcn_rcpf)
    return __builtin_amdgcn_rcpf(x);
#else
    return 1.0f / x;
#endif
}

// pack two positive floats to bf16x2 (round-half-up), lo in low 16 bits
__device__ __forceinline__ unsigned int pack_bf16x2(float lo, float hi) {
    unsigned int a = __float_as_uint(lo) + 0x8000u;
    unsigned int b = __float_as_uint(hi) + 0x8000u;
#if __has_builtin(__builtin_amdgcn_perm)
    return __builtin_amdgcn_perm(b, a, 0x07060302u);
#else
    return (a >> 16) | (b & 0xFFFF0000u);
#endif
}

// ---------------- fp32 -> bf16 convert (4 elems/thread), both tensors ------
// R8-proven: merged into one dispatch (saves a launch, ~6 us).
__global__ void cvt_bf16_2(const float* __restrict__ a,
                           unsigned short* __restrict__ oa, int n4a,
                           const float* __restrict__ bsrc,
                           unsigned short* __restrict__ ob, int n4b) {
    int i = blockIdx.x * blockDim.x + threadIdx.x;
    if (i < n4a) {
        float4 v = ((const float4*)a)[i];
        ushort4 o;
        o.x = f2bf(v.x); o.y = f2bf(v.y); o.z = f2bf(v.z); o.w = f2bf(v.w);
        ((ushort4*)oa)[i] = o;
    } else {
        int j = i - n4a;
        if (j < n4b) {
            float4 v = ((const float4*)bsrc)[j];
            ushort4 o;
            o.x = f2bf(v.x); o.y = f2bf(v.y); o.z = f2bf(v.z); o.w = f2bf(v.w);
            ((ushort4*)ob)[j] = o;
        }
    }
}

// ---------------- QKV projection GEMM ----------------
// R11: 4-phase counted-vmcnt pipeline (T3/T4). BK=64, 16 K-tiles.
// 1x4 wave grid: per-wave 128 rows x 32 cols, acc[8][2]. Panels = 64-row
// halves of the A/B tiles, double-buffered (LDS 64KB -> 2 blocks/CU).
// Phase p of tile T: {ds_read frags; stage ONE panel of tile T+1 into the
// other buffer; [vmcnt(4)@p1 / vmcnt(2)@p3]; s_barrier; 8 MFMA; s_barrier}.
// Panel lifetimes: A0 read p0,p1 / A1 read p2,p3 / B0,B1 read all phases.
// Stage slots: p0->B'(0), p1->B'(1), p2->A'(0), p3->A'(1) — each targets a
// slot whose last read was >=1 barrier earlier. vmcnt never drains to 0 in
// the loop. Per-accumulator K-order identical to the 2-phase kernel ->
// bit-identical output (absmax canary).
// Chunk-XOR swizzle (R7-proven): LDS phys chunk c holds logical c^(row&7);
// staged via pre-swizzled global source col; read at (kh*4+quad)^(l15&7).
__global__ __launch_bounds__(256) void qkv_gemm(
    const unsigned short* __restrict__ Xb,
    const unsigned short* __restrict__ Wb,
    unsigned short* __restrict__ Qo,
    unsigned short* __restrict__ Ko,
    unsigned short* __restrict__ Vt)
{
    __shared__ __align__(16) unsigned short As[2 * 8192];
    __shared__ __align__(16) unsigned short Bs[2 * 8192];

    const int t    = threadIdx.x;
    // XCD swizzle (1536 blocks, bijective)
    const int flat = blockIdx.y * 24 + blockIdx.x;
    const int sw   = (flat & 7) * 192 + (flat >> 3);
    const int m0   = (sw / 24) * 128;
    const int n0   = (sw % 24) * 128;

    const int wn   = t >> 6;        // wave id = N-column position (1x4)
    const int lane = t & 63;
    const int l15  = lane & 15;
    const int quad = lane >> 4;

    // staging source (per-thread): row srow (0..31), pre-swizzled col chunk
    const int srow = t >> 3;
    const int csrc = ((t & 7) ^ (srow & 7)) * 8;
    const unsigned short* gA = &Xb[(size_t)(m0 + srow) * 1024 + csrc];
    const unsigned short* gB = &Wb[(size_t)(n0 + srow) * 1024 + csrc];
    const int ldst = t * 8;         // lane-linear LDS elems within r-section

    // fragment read chunk offsets (kh = 0/1)
    const int x7  = l15 & 7;
    const int ck0 = (quad ^ x7) * 8;
    const int ck1 = ((4 + quad) ^ x7) * 8;

    f32x4 acc[8][2] = {};

    auto stageA = [&](int h, int kt, int bufE) {
        #pragma unroll
        for (int r = 0; r < 2; r++)
            __builtin_amdgcn_global_load_lds(
                (gas_t)(const void*)(gA + h * 65536 + r * 32768 + kt * 64),
                (las_t)(void*)&As[bufE + h * 4096 + r * 2048 + ldst], 16, 0, 0);
    };
    auto stageB = [&](int h, int kt, int bufE) {
        #pragma unroll
        for (int r = 0; r < 2; r++)
            __builtin_amdgcn_global_load_lds(
                (gas_t)(const void*)(gB + h * 65536 + r * 32768 + kt * 64),
                (las_t)(void*)&Bs[bufE + h * 4096 + r * 2048 + ldst], 16, 0, 0);
    };

    // -------- prologue: stage tile 0 (order B0,B1,A0,A1) --------
    stageB(0, 0, 0); stageB(1, 0, 0); stageA(0, 0, 0); stageA(1, 0, 0);
    asm volatile("s_waitcnt vmcnt(2)" ::: "memory");   // A0,B0,B1 landed
    __builtin_amdgcn_s_barrier();
    asm volatile("" ::: "memory");

    #pragma unroll 1
    for (int kt = 0; kt < 16; kt++) {
        const int buf  = (kt & 1) * 8192;
        const int obuf = 8192 - buf;
        const int ktn  = (kt < 15) ? kt + 1 : 15;   // tile15 re-stage: benign

        // ---- p0: quadrant (mh=0, kh=0); stage B'(0) ----
        {
            s16x8 af[4], bf[2];
            #pragma unroll
            for (int i = 0; i < 4; i++)
                af[i] = *(const s16x8*)&As[buf + (i * 16 + l15) * 64 + ck0];
            #pragma unroll
            for (int j = 0; j < 2; j++)
                bf[j] = *(const s16x8*)&Bs[buf + (wn * 32 + j * 16 + l15) * 64 + ck0];
            stageB(0, ktn, obuf);
            asm volatile("" ::: "memory");
            __builtin_amdgcn_s_barrier();
            asm volatile("" ::: "memory");
            #pragma unroll
            for (int i = 0; i < 4; i++)
                #pragma unroll
                for (int j = 0; j < 2; j++)
                    acc[i][j] = __builtin_amdgcn_mfma_f32_16x16x32_bf16(
                        af[i], bf[j], acc[i][j], 0, 0, 0);
            asm volatile("" ::: "memory");
            __builtin_amdgcn_s_barrier();
            asm volatile("" ::: "memory");
        }
        // ---- p1: (0,1); stage B'(1); vmcnt(4) covers A(T)'s A1 for p2 ----
        {
            s16x8 af[4], bf[2];
            #pragma unroll
            for (int i = 0; i < 4; i++)
                af[i] = *(const s16x8*)&As[buf + (i * 16 + l15) * 64 + ck1];
            #pragma unroll
            for (int j = 0; j < 2; j++)
                bf[j] = *(const s16x8*)&Bs[buf + (wn * 32 + j * 16 + l15) * 64 + ck1];
            stageB(1, ktn, obuf);
            asm volatile("s_waitcnt vmcnt(4)" ::: "memory");
            __builtin_amdgcn_s_barrier();
            asm volatile("" ::: "memory");
            #pragma unroll
            for (int i = 0; i < 4; i++)
                #pragma unroll
                for (int j = 0; j < 2; j++)
                    acc[i][j] = __builtin_amdgcn_mfma_f32_16x16x32_bf16(
                        af[i], bf[j], acc[i][j], 0, 0, 0);
            asm volatile("" ::: "memory");
            __builtin_amdgcn_s_barrier();
            asm volatile("" ::: "memory");
        }
        // ---- p2: (1,0); stage A'(0) ----
        {
            s16x8 af[4], bf[2];
            #pragma unroll
            for (int i = 0; i < 4; i++)
                af[i] = *(const s16x8*)&As[buf + (64 + i * 16 + l15) * 64 + ck0];
            #pragma unroll
            for (int j = 0; j < 2; j++)
                bf[j] = *(const s16x8*)&Bs[buf + (wn * 32 + j * 16 + l15) * 64 + ck0];
            stageA(0, ktn, obuf);
            asm volatile("" ::: "memory");
            __builtin_amdgcn_s_barrier();
            asm volatile("" ::: "memory");
            #pragma unroll
            for (int i = 0; i < 4; i++)
                #pragma unroll
                for (int j = 0; j < 2; j++)
                    acc[4 + i][j] = __builtin_amdgcn_mfma_f32_16x16x32_bf16(
                        af[i], bf[j], acc[4 + i][j], 0, 0, 0);
            asm volatile("" ::: "memory");
            __builtin_amdgcn_s_barrier();
            asm volatile("" ::: "memory");
        }
        // ---- p3: (1,1); stage A'(1); vmcnt(2) covers A'(0),B'(0),B'(1) ----
        {
            s16x8 af[4], bf[2];
            #pragma unroll
            for (int i = 0; i < 4; i++)
                af[i] = *(const s16x8*)&As[buf + (64 + i * 16 + l15) * 64 + ck1];
            #pragma unroll
            for (int j = 0; j < 2; j++)
                bf[j] = *(const s16x8*)&Bs[buf + (wn * 32 + j * 16 + l15) * 64 + ck1];
            stageA(1, ktn, obuf);
            asm volatile("s_waitcnt vmcnt(2)" ::: "memory");
            __builtin_amdgcn_s_barrier();
            asm volatile("" ::: "memory");
            #pragma unroll
            for (int i = 0; i < 4; i++)
                #pragma unroll
                for (int j = 0; j < 2; j++)
                    acc[4 + i][j] = __builtin_amdgcn_mfma_f32_16x16x32_bf16(
                        af[i], bf[j], acc[4 + i][j], 0, 0, 0);
            asm volatile("" ::: "memory");
            __builtin_amdgcn_s_barrier();
            asm volatile("" ::: "memory");
        }
    }
    // drain: no DMA may outlive the workgroup's LDS allocation
    asm volatile("s_waitcnt vmcnt(0)" ::: "memory");

    // -------- epilogue: split C into Q (scaled), K, V^T --------
    #pragma unroll
    for (int mrep = 0; mrep < 8; mrep++) {
        const int mbase = m0 + mrep * 16 + quad * 4;
        const int b     = mbase >> 11;
        const int nbase = mbase & 2047;
        #pragma unroll
        for (int nrep = 0; nrep < 2; nrep++) {
            const int o  = n0 + wn * 32 + nrep * 16 + l15;
            const int p  = o >> 10;
            const int oo = o & 1023;
            const int h  = oo >> 6;
            const int d  = oo & 63;
            if (p == 0) {
                #pragma unroll
                for (int r = 0; r < 4; r++)
                    Qo[((size_t)(b * 16 + h) * 2048 + nbase + r) * 64 + d] =
                        f2bf(acc[mrep][nrep][r] * QSC);
            } else if (p == 1) {
                #pragma unroll
                for (int r = 0; r < 4; r++)
                    Ko[((size_t)(b * 16 + h) * 2048 + nbase + r) * 64 + d] =
                        f2bf(acc[mrep][nrep][r]);
            } else {
                ushort4 v4;
                v4.x = f2bf(acc[mrep][nrep][0]);
                v4.y = f2bf(acc[mrep][nrep][1]);
                v4.z = f2bf(acc[mrep][nrep][2]);
                v4.w = f2bf(acc[mrep][nrep][3]);
                *(ushort4*)&Vt[((size_t)(b * 16 + h) * 64 + d) * 2048 + nbase] = v4;
            }
        }
    }
}

// ---------------- fused attention ----------------
// R7-proven, reverted verbatim (R10's V-direct-read regressed: vb global
// loads share the in-order vmcnt with K-staging DMA -> PV waits serialized
// the prefetch). K/V staged via global_load_lds (async, double-buffered),
// XOR swizzle for conflict-free ds_read_b128, softmax with pack_bf16x2,
// row sums via ones-column MFMA, shared zero-C for QK^T. No setprio (R8).
#define PSTRIDE 72
#define PBASE   16384

__global__ __launch_bounds__(256) void attn(
    const unsigned short* __restrict__ Q,
    const unsigned short* __restrict__ K,
    const unsigned short* __restrict__ Vt,
    float* __restrict__ out)
{
    __shared__ __align__(16) unsigned short LDS[PBASE + 4 * 32 * PSTRIDE];

    const int t    = threadIdx.x;
    const int w    = t >> 6;
    const int lane = t & 63;
    const int l15  = lane & 15;
    const int quad = lane >> 4;
    const int head = blockIdx.y;            // b*16 + h
    const int b    = head >> 4;
    const int h    = head & 15;
    const int q0   = blockIdx.x * 128 + w * 32;

    const unsigned short* Qh = Q  + (size_t)head * 2048 * 64;
    const unsigned short* Kh = K  + (size_t)head * 2048 * 64;
    const unsigned short* Vh = Vt + (size_t)head * 64 * 2048;

    // ---- staging source addresses (per thread, lane-linear LDS dst) ----
    // phys chunk i = rd*256 + t holds logical (row=i>>3, col=(i&7)^(row&7))
    const int r0 = t >> 3;                    // 0..31 (round 1 adds 32)
    const int c0 = (t & 7) ^ (r0 & 7);
    const unsigned short* srcK = Kh + r0 * 64 + c0 * 8;
    const unsigned short* srcV = Vh + r0 * 2048 + c0 * 8;

    auto stageKV = [&](int kt, int bufE) {
        #pragma unroll
        for (int rd = 0; rd < 2; rd++) {
            __builtin_amdgcn_global_load_lds(
                (gas_t)(const void*)(srcK + kt * 4096 + rd * 2048),
                (las_t)(void*)&LDS[bufE + rd * 2048 + w * 512], 16, 0, 0);
            __builtin_amdgcn_global_load_lds(
                (gas_t)(const void*)(srcV + kt * 64 + rd * 65536),
                (las_t)(void*)&LDS[bufE + 4096 + rd * 2048 + w * 512], 16, 0, 0);
        }
    };

    // Q fragments (pre-scaled by QSC in gemm), B-operand role
    s16x8 qb[2][2];
    #pragma unroll
    for (int mt = 0; mt < 2; mt++)
        #pragma unroll
        for (int kc = 0; kc < 2; kc++)
            qb[mt][kc] = *(const s16x8*)&Qh[(size_t)(q0 + mt * 16 + l15) * 64 + kc * 32 + quad * 8];

    // ones B-fragment (bf16 1.0) for MFMA row-sums
    s16x8 onesf;
    #pragma unroll
    for (int i = 0; i < 8; i++) onesf[i] = (short)0x3F80;
    const f32x4 fz = {0.f, 0.f, 0.f, 0.f};

    f32x4 y[2][4] = {};
    f32x4 ysum[2] = {};
    unsigned short* P = &LDS[PBASE + w * (32 * PSTRIDE)];

    // swizzled in-tile column offsets (elems) for kc=0/1
    const int x7   = l15 & 7;
    const int csw0 = (quad ^ x7) * 8;
    const int csw1 = ((4 + quad) ^ x7) * 8;

    auto compute = [&](int bufE) {
        // K fragments from LDS
        s16x8 kb[4][2];
        #pragma unroll
        for (int nt = 0; nt < 4; nt++) {
            const int rowb = bufE + (nt * 16 + l15) * 64;
            kb[nt][0] = *(const s16x8*)&LDS[rowb + csw0];
            kb[nt][1] = *(const s16x8*)&LDS[rowb + csw1];
        }
        // S^T = K * Q^T  (kc=0 consumes shared zero C; kc=1 accumulates)
        f32x4 st[4][2];
        #pragma unroll
        for (int nt = 0; nt < 4; nt++)
            #pragma unroll
            for (int mt = 0; mt < 2; mt++)
                st[nt][mt] = __builtin_amdgcn_mfma_f32_16x16x32_bf16(
                    kb[nt][0], qb[mt][0], fz, 0, 0, 0);
        #pragma unroll
        for (int nt = 0; nt < 4; nt++)
            #pragma unroll
            for (int mt = 0; mt < 2; mt++)
                st[nt][mt] = __builtin_amdgcn_mfma_f32_16x16x32_bf16(
                    kb[nt][1], qb[mt][1], st[nt][mt], 0, 0, 0);
        // V fragments from LDS (issued before the exp block)
        s16x8 vb[4][2];
        #pragma unroll
        for (int dt = 0; dt < 4; dt++) {
            const int rowb = bufE + 4096 + (dt * 16 + l15) * 64;
            vb[dt][0] = *(const s16x8*)&LDS[rowb + csw0];
            vb[dt][1] = *(const s16x8*)&LDS[rowb + csw1];
        }
        // exp2 + pack + ds_write_b64 into per-wave P region
        #pragma unroll
        for (int mt = 0; mt < 2; mt++)
            #pragma unroll
            for (int nt = 0; nt < 4; nt++) {
                float p0 = exp2_fast(st[nt][mt][0]);
                float p1 = exp2_fast(st[nt][mt][1]);
                float p2 = exp2_fast(st[nt][mt][2]);
                float p3 = exp2_fast(st[nt][mt][3]);
                uint2 u;
                u.x = pack_bf16x2(p0, p1);
                u.y = pack_bf16x2(p2, p3);
                *(uint2*)&P[(mt * 16 + l15) * PSTRIDE + nt * 16 + quad * 4] = u;
            }
        // Y += P V ; row sums via ones-MFMA (denominator = bf16 P, consistent
        // with the PV numerator)
        #pragma unroll
        for (int kc = 0; kc < 2; kc++) {
            s16x8 pa[2];
            #pragma unroll
            for (int mt = 0; mt < 2; mt++)
                pa[mt] = *(const s16x8*)&P[(mt * 16 + l15) * PSTRIDE + kc * 32 + quad * 8];
            #pragma unroll
            for (int mt = 0; mt < 2; mt++)
                ysum[mt] = __builtin_amdgcn_mfma_f32_16x16x32_bf16(
                    pa[mt], onesf, ysum[mt], 0, 0, 0);
            #pragma unroll
            for (int mt = 0; mt < 2; mt++)
                #pragma unroll
                for (int dt = 0; dt < 4; dt++)
                    y[mt][dt] = __builtin_amdgcn_mfma_f32_16x16x32_bf16(
                        pa[mt], vb[dt][kc], y[mt][dt], 0, 0, 0);
        }
    };

    // -------- prologue --------
    stageKV(0, 0);
    __syncthreads();            // drain (vmcnt 0) + barrier: buf0 ready

    // -------- main loop: issue next (other buffer) -> compute -> barrier ----
    #pragma unroll 1
    for (int kt = 0; kt < 32; kt += 2) {
        stageKV(kt + 1, 8192);          // kt+1 <= 31 always
        compute(0);
        __syncthreads();
        if (kt + 2 < 32) stageKV(kt + 2, 0);
        compute(8192);
        __syncthreads();
    }

    // ysum[mt][r] holds the full row sum for q-row = mt*16 + quad*4 + r
    float rinv[2][4];
    #pragma unroll
    for (int mt = 0; mt < 2; mt++)
        #pragma unroll
        for (int r = 0; r < 4; r++)
            rinv[mt][r] = rcp_fast(ysum[mt][r]);

    // out[b, n, h*64+d] fp32; C-layout: col=l15 -> d, row=quad*4+r -> m
    #pragma unroll
    for (int mt = 0; mt < 2; mt++)
        #pragma unroll
        for (int dt = 0; dt < 4; dt++)
            #pragma unroll
            for (int r = 0; r < 4; r++) {
                const int n = q0 + mt * 16 + quad * 4 + r;
                const int d = dt * 16 + l15;
                out[((size_t)(b * 2048 + n)) * 1024 + h * 64 + d] =
                    y[mt][dt][r] * rinv[mt][r];
            }
}

// ---------------- launch ----------------
extern "C" void kernel_launch(void* const* d_in, const int* in_sizes, int n_in,
                              void* d_out, int out_size, void* d_ws, size_t ws_size,
                              hipStream_t stream) {
    const float* X = (const float*)d_in[0];   // [4,2048,1024]
    const float* W = (const float*)d_in[1];   // [3072,1024]
    float* out = (float*)d_out;

    char* ws = (char*)d_ws;
    unsigned short* Xb = (unsigned short*)(ws);                 // 16.8 MB
    unsigned short* Wb = (unsigned short*)(ws + 16777216);      //  6.3 MB
    unsigned short* Qb = (unsigned short*)(ws + 23068672);      // 16.8 MB
    unsigned short* Kb = (unsigned short*)(ws + 39845888);      // 16.8 MB
    unsigned short* Vt = (unsigned short*)(ws + 56623104);      // 16.8 MB (ends 73.4 MB)

    cvt_bf16_2<<<dim3(11264), dim3(256), 0, stream>>>(X, Xb, 2097152, W, Wb, 786432);
    qkv_gemm<<<dim3(24, 64), dim3(256), 0, stream>>>(Xb, Wb, Qb, Kb, Vt);
    attn<<<dim3(16, 64), dim3(256), 0, stream>>>(Qb, Kb, Vt, out);
}

// Round 12
// 244.086 us; speedup vs baseline: 1.2181x; 1.0284x over previous
//
#include <hip/hip_runtime.h>

// Problem constants
#define BATCH   4
#define SEQ     2048
#define DMODEL  1024
#define NHEADS  16
#define HDIM    64
// SCALE * log2(e) folded into Q at the GEMM epilogue: exp(s*0.125) = exp2(s*QSC)
#define QSC     0.18033688f

typedef short s16x8 __attribute__((ext_vector_type(8)));
typedef float f32x4 __attribute__((ext_vector_type(4)));
typedef const __attribute__((address_space(1))) unsigned int* gas_t;
typedef __attribute__((address_space(3))) unsigned int* las_t;

__device__ inline unsigned short f2bf(float f) {
    unsigned int u = __float_as_uint(f);
    u += 0x7FFF + ((u >> 16) & 1);   // RNE
    return (unsigned short)(u >> 16);
}

__device__ __forceinline__ float exp2_fast(float x) {
#if __has_builtin(__builtin_amdgcn_exp2f)
    return __builtin_amdgcn_exp2f(x);
#else
    return exp2f(x);
#endif
}

__device__ __forceinline__ float rcp_fast(float x) {
#if __has_builtin(__builtin_amdgcn_rcpf)
    return __builtin_amdgcn_rcpf(x);
#else
    return 1.0f / x;
#endif
}

// pack two positive floats to bf16x2 (round-half-up), lo in low 16 bits
__device__ __forceinline__ unsigned int pack_bf16x2(float lo, float hi) {
    unsigned int a = __float_as_uint(lo) + 0x8000u;
    unsigned int b = __float_as_uint(hi) + 0x8000u;
#if __has_builtin(__builtin_amdgcn_perm)
    return __builtin_amdgcn_perm(b, a, 0x07060302u);
#else
    return (a >> 16) | (b & 0xFFFF0000u);
#endif
}

// ---------------- fp32 -> bf16 convert (4 elems/thread), both tensors ------
// R8-proven: merged into one dispatch.
__global__ void cvt_bf16_2(const float* __restrict__ a,
                           unsigned short* __restrict__ oa, int n4a,
                           const float* __restrict__ bsrc,
                           unsigned short* __restrict__ ob, int n4b) {
    int i = blockIdx.x * blockDim.x + threadIdx.x;
    if (i < n4a) {
        float4 v = ((const float4*)a)[i];
        ushort4 o;
        o.x = f2bf(v.x); o.y = f2bf(v.y); o.z = f2bf(v.z); o.w = f2bf(v.w);
        ((ushort4*)oa)[i] = o;
    } else {
        int j = i - n4a;
        if (j < n4b) {
            float4 v = ((const float4*)bsrc)[j];
            ushort4 o;
            o.x = f2bf(v.x); o.y = f2bf(v.y); o.z = f2bf(v.z); o.w = f2bf(v.w);
            ((ushort4*)ob)[j] = o;
        }
    }
}

// ---------------- QKV projection GEMM ----------------
// R8-proven 2-phase (reverted from R11's 4-phase: measured equal, simpler).
// global_load_lds staging + XCD swizzle + dbuf + chunk-XOR bank swizzle.
__global__ __launch_bounds__(256) void qkv_gemm(
    const unsigned short* __restrict__ Xb,
    const unsigned short* __restrict__ Wb,
    unsigned short* __restrict__ Qo,
    unsigned short* __restrict__ Ko,
    unsigned short* __restrict__ Vt)
{
    __shared__ __align__(16) unsigned short As[2 * 128 * 32];
    __shared__ __align__(16) unsigned short Bs[2 * 128 * 32];

    const int t    = threadIdx.x;
    // XCD swizzle: flat in dispatch order (x fastest), 8 XCDs round-robin
    const int flat = blockIdx.y * 24 + blockIdx.x;
    const int sw   = (flat & 7) * 192 + (flat >> 3);
    const int m0   = (sw / 24) * 128;
    const int n0   = (sw % 24) * 128;

    const int wid  = t >> 6;
    const int lane = t & 63;
    const int l15  = lane & 15;
    const int quad = lane >> 4;
    const int wm   = (wid >> 1) * 64;
    const int wn   = (wid & 1) * 64;

    // staging: wave w covers tile rows w*32 .. w*32+31 (2 chunks of 16 rows)
    const int rA   = wid * 32 + (lane >> 2);      // + rd*16 (rd*16 doesn't change (rA>>1)&3)
    const int kcol_phys = (lane & 3) * 8;                          // LDS (lane-linear)
    const int kcol_src  = ((lane & 3) ^ ((rA >> 1) & 3)) * 8;      // global (pre-swizzled)
    const unsigned short* gA = &Xb[(size_t)(m0 + rA) * 1024 + kcol_src];
    const unsigned short* gB = &Wb[(size_t)(n0 + rA) * 1024 + kcol_src];

    // swizzled read chunk: logical chunk = quad, phys = quad ^ ((l15>>1)&3)
    const int cswq = (quad ^ ((l15 >> 1) & 3)) * 8;

    f32x4 acc[4][4] = {};

    auto stage = [&](int k0, int bufE) {
        #pragma unroll
        for (int rd = 0; rd < 2; rd++) {
            __builtin_amdgcn_global_load_lds(
                (gas_t)(const void*)(gA + rd * 16 * 1024 + k0),
                (las_t)(void*)&As[bufE + (rA + rd * 16) * 32 + kcol_phys], 16, 0, 0);
            __builtin_amdgcn_global_load_lds(
                (gas_t)(const void*)(gB + rd * 16 * 1024 + k0),
                (las_t)(void*)&Bs[bufE + (rA + rd * 16) * 32 + kcol_phys], 16, 0, 0);
        }
    };

    auto comp = [&](int bufE) {
        s16x8 af[4], bf[4];
        #pragma unroll
        for (int mt = 0; mt < 4; mt++)
            af[mt] = *(const s16x8*)&As[bufE + (wm + mt * 16 + l15) * 32 + cswq];
        #pragma unroll
        for (int nt = 0; nt < 4; nt++)
            bf[nt] = *(const s16x8*)&Bs[bufE + (wn + nt * 16 + l15) * 32 + cswq];
        #pragma unroll
        for (int mt = 0; mt < 4; mt++)
            #pragma unroll
            for (int nt = 0; nt < 4; nt++)
                acc[mt][nt] = __builtin_amdgcn_mfma_f32_16x16x32_bf16(
                    af[mt], bf[nt], acc[mt][nt], 0, 0, 0);
    };

    // prologue
    stage(0, 0);
    __syncthreads();            // vmcnt(0) drain + barrier: buf0 ready

    #pragma unroll 1
    for (int k0 = 0; k0 < 1024; k0 += 64) {
        stage(k0 + 32, 4096);   // k0+32 <= 992 always
        comp(0);
        __syncthreads();        // drains buf1 DMA; buf0 compute done
        if (k0 + 64 < 1024) stage(k0 + 64, 0);
        comp(4096);
        __syncthreads();
    }

    #pragma unroll
    for (int mt = 0; mt < 4; mt++) {
        const int mbase = m0 + wm + mt * 16 + quad * 4;
        const int b     = mbase >> 11;
        const int nbase = mbase & 2047;
        #pragma unroll
        for (int nt = 0; nt < 4; nt++) {
            const int o  = n0 + wn + nt * 16 + l15;
            const int p  = o >> 10;
            const int oo = o & 1023;
            const int h  = oo >> 6;
            const int d  = oo & 63;
            if (p == 0) {
                #pragma unroll
                for (int r = 0; r < 4; r++)
                    Qo[((size_t)(b * 16 + h) * 2048 + nbase + r) * 64 + d] =
                        f2bf(acc[mt][nt][r] * QSC);
            } else if (p == 1) {
                #pragma unroll
                for (int r = 0; r < 4; r++)
                    Ko[((size_t)(b * 16 + h) * 2048 + nbase + r) * 64 + d] =
                        f2bf(acc[mt][nt][r]);
            } else {
                ushort4 v4;
                v4.x = f2bf(acc[mt][nt][0]);
                v4.y = f2bf(acc[mt][nt][1]);
                v4.z = f2bf(acc[mt][nt][2]);
                v4.w = f2bf(acc[mt][nt][3]);
                *(ushort4*)&Vt[((size_t)(b * 16 + h) * 64 + d) * 2048 + nbase] = v4;
            }
        }
    }
}

// ---------------- fused attention ----------------
// R12: 8-wave blocks (512 threads), 256 q-rows/block, grid (8,64) = 512
// blocks = exactly 2/CU -> 16 waves/CU (+33% TLP vs 12). Pure
// re-partitioning: per-wave instruction stream identical to the R7-proven
// 4-wave version; each staged K/V tile now feeds 8 waves (per-head K/V
// fetched 8x instead of 16x -> FETCH_SIZE halves). stageKV collapses to one
// DMA pair per thread (512 x 16B = full 8KB tile).
// LDS map (ushort elems): K0@0, V0@4096, K1@8192, V1@12288, P@16384+w*2304.
#define PSTRIDE 72
#define PBASE   16384

__global__ __launch_bounds__(512) void attn(
    const unsigned short* __restrict__ Q,
    const unsigned short* __restrict__ K,
    const unsigned short* __restrict__ Vt,
    float* __restrict__ out)
{
    __shared__ __align__(16) unsigned short LDS[PBASE + 8 * 32 * PSTRIDE];

    const int t    = threadIdx.x;
    const int w    = t >> 6;                // 0..7
    const int lane = t & 63;
    const int l15  = lane & 15;
    const int quad = lane >> 4;
    const int head = blockIdx.y;            // b*16 + h
    const int b    = head >> 4;
    const int h    = head & 15;
    const int q0   = blockIdx.x * 256 + w * 32;

    const unsigned short* Qh = Q  + (size_t)head * 2048 * 64;
    const unsigned short* Kh = K  + (size_t)head * 2048 * 64;
    const unsigned short* Vh = Vt + (size_t)head * 64 * 2048;

    // ---- staging source addresses (per thread, lane-linear LDS dst) ----
    // phys chunk i = t holds logical (row=i>>3, col=(i&7)^(row&7)); 512
    // threads cover all 64 rows x 8 chunks in one DMA round.
    const int r0 = t >> 3;                    // 0..63
    const int c0 = (t & 7) ^ (r0 & 7);
    const unsigned short* srcK = Kh + r0 * 64 + c0 * 8;
    const unsigned short* srcV = Vh + r0 * 2048 + c0 * 8;

    auto stageKV = [&](int kt, int bufE) {
        __builtin_amdgcn_global_load_lds(
            (gas_t)(const void*)(srcK + kt * 4096),
            (las_t)(void*)&LDS[bufE + t * 8], 16, 0, 0);
        __builtin_amdgcn_global_load_lds(
            (gas_t)(const void*)(srcV + kt * 64),
            (las_t)(void*)&LDS[bufE + 4096 + t * 8], 16, 0, 0);
    };

    // Q fragments (pre-scaled by QSC in gemm), B-operand role
    s16x8 qb[2][2];
    #pragma unroll
    for (int mt = 0; mt < 2; mt++)
        #pragma unroll
        for (int kc = 0; kc < 2; kc++)
            qb[mt][kc] = *(const s16x8*)&Qh[(size_t)(q0 + mt * 16 + l15) * 64 + kc * 32 + quad * 8];

    // ones B-fragment (bf16 1.0) for MFMA row-sums
    s16x8 onesf;
    #pragma unroll
    for (int i = 0; i < 8; i++) onesf[i] = (short)0x3F80;
    const f32x4 fz = {0.f, 0.f, 0.f, 0.f};

    f32x4 y[2][4] = {};
    f32x4 ysum[2] = {};
    unsigned short* P = &LDS[PBASE + w * (32 * PSTRIDE)];

    // swizzled in-tile column offsets (elems) for kc=0/1
    const int x7   = l15 & 7;
    const int csw0 = (quad ^ x7) * 8;
    const int csw1 = ((4 + quad) ^ x7) * 8;

    auto compute = [&](int bufE) {
        // K fragments from LDS
        s16x8 kb[4][2];
        #pragma unroll
        for (int nt = 0; nt < 4; nt++) {
            const int rowb = bufE + (nt * 16 + l15) * 64;
            kb[nt][0] = *(const s16x8*)&LDS[rowb + csw0];
            kb[nt][1] = *(const s16x8*)&LDS[rowb + csw1];
        }
        // S^T = K * Q^T  (kc=0 consumes shared zero C; kc=1 accumulates)
        f32x4 st[4][2];
        #pragma unroll
        for (int nt = 0; nt < 4; nt++)
            #pragma unroll
            for (int mt = 0; mt < 2; mt++)
                st[nt][mt] = __builtin_amdgcn_mfma_f32_16x16x32_bf16(
                    kb[nt][0], qb[mt][0], fz, 0, 0, 0);
        #pragma unroll
        for (int nt = 0; nt < 4; nt++)
            #pragma unroll
            for (int mt = 0; mt < 2; mt++)
                st[nt][mt] = __builtin_amdgcn_mfma_f32_16x16x32_bf16(
                    kb[nt][1], qb[mt][1], st[nt][mt], 0, 0, 0);
        // V fragments from LDS (issued before the exp block)
        s16x8 vb[4][2];
        #pragma unroll
        for (int dt = 0; dt < 4; dt++) {
            const int rowb = bufE + 4096 + (dt * 16 + l15) * 64;
            vb[dt][0] = *(const s16x8*)&LDS[rowb + csw0];
            vb[dt][1] = *(const s16x8*)&LDS[rowb + csw1];
        }
        // exp2 + pack + ds_write_b64 into per-wave P region
        #pragma unroll
        for (int mt = 0; mt < 2; mt++)
            #pragma unroll
            for (int nt = 0; nt < 4; nt++) {
                float p0 = exp2_fast(st[nt][mt][0]);
                float p1 = exp2_fast(st[nt][mt][1]);
                float p2 = exp2_fast(st[nt][mt][2]);
                float p3 = exp2_fast(st[nt][mt][3]);
                uint2 u;
                u.x = pack_bf16x2(p0, p1);
                u.y = pack_bf16x2(p2, p3);
                *(uint2*)&P[(mt * 16 + l15) * PSTRIDE + nt * 16 + quad * 4] = u;
            }
        // Y += P V ; row sums via ones-MFMA (denominator = bf16 P, consistent
        // with the PV numerator)
        #pragma unroll
        for (int kc = 0; kc < 2; kc++) {
            s16x8 pa[2];
            #pragma unroll
            for (int mt = 0; mt < 2; mt++)
                pa[mt] = *(const s16x8*)&P[(mt * 16 + l15) * PSTRIDE + kc * 32 + quad * 8];
            #pragma unroll
            for (int mt = 0; mt < 2; mt++)
                ysum[mt] = __builtin_amdgcn_mfma_f32_16x16x32_bf16(
                    pa[mt], onesf, ysum[mt], 0, 0, 0);
            #pragma unroll
            for (int mt = 0; mt < 2; mt++)
                #pragma unroll
                for (int dt = 0; dt < 4; dt++)
                    y[mt][dt] = __builtin_amdgcn_mfma_f32_16x16x32_bf16(
                        pa[mt], vb[dt][kc], y[mt][dt], 0, 0, 0);
        }
    };

    // -------- prologue --------
    stageKV(0, 0);
    __syncthreads();            // drain (vmcnt 0) + barrier: buf0 ready

    // -------- main loop: issue next (other buffer) -> compute -> barrier ----
    #pragma unroll 1
    for (int kt = 0; kt < 32; kt += 2) {
        stageKV(kt + 1, 8192);          // kt+1 <= 31 always
        compute(0);
        __syncthreads();
        if (kt + 2 < 32) stageKV(kt + 2, 0);
        compute(8192);
        __syncthreads();
    }

    // ysum[mt][r] holds the full row sum for q-row = mt*16 + quad*4 + r
    float rinv[2][4];
    #pragma unroll
    for (int mt = 0; mt < 2; mt++)
        #pragma unroll
        for (int r = 0; r < 4; r++)
            rinv[mt][r] = rcp_fast(ysum[mt][r]);

    // out[b, n, h*64+d] fp32; C-layout: col=l15 -> d, row=quad*4+r -> m
    #pragma unroll
    for (int mt = 0; mt < 2; mt++)
        #pragma unroll
        for (int dt = 0; dt < 4; dt++)
            #pragma unroll
            for (int r = 0; r < 4; r++) {
                const int n = q0 + mt * 16 + quad * 4 + r;
                const int d = dt * 16 + l15;
                out[((size_t)(b * 2048 + n)) * 1024 + h * 64 + d] =
                    y[mt][dt][r] * rinv[mt][r];
            }
}

// ---------------- launch ----------------
extern "C" void kernel_launch(void* const* d_in, const int* in_sizes, int n_in,
                              void* d_out, int out_size, void* d_ws, size_t ws_size,
                              hipStream_t stream) {
    const float* X = (const float*)d_in[0];   // [4,2048,1024]
    const float* W = (const float*)d_in[1];   // [3072,1024]
    float* out = (float*)d_out;

    char* ws = (char*)d_ws;
    unsigned short* Xb = (unsigned short*)(ws);                 // 16.8 MB
    unsigned short* Wb = (unsigned short*)(ws + 16777216);      //  6.3 MB
    unsigned short* Qb = (unsigned short*)(ws + 23068672);      // 16.8 MB
    unsigned short* Kb = (unsigned short*)(ws + 39845888);      // 16.8 MB
    unsigned short* Vt = (unsigned short*)(ws + 56623104);      // 16.8 MB (ends 73.4 MB)

    cvt_bf16_2<<<dim3(11264), dim3(256), 0, stream>>>(X, Xb, 2097152, W, Wb, 786432);
    qkv_gemm<<<dim3(24, 64), dim3(256), 0, stream>>>(Xb, Wb, Qb, Kb, Vt);
    attn<<<dim3(8, 64), dim3(512), 0, stream>>>(Qb, Kb, Vt, out);
}